// Round 16
// baseline (521.820 us; speedup 1.0000x reference)
//
#include <hip/hip_runtime.h>
#include <hip/hip_bf16.h>

#define EPSV 1e-5

__device__ __forceinline__ float fsign(float x) {
    return (float)((x > 0.f) - (x < 0.f));
}

// ---------------- sign(weights) for fc1, fc2, fc3 ----------------
struct WPtrs {
    const float* src[3];
    float* dst[3];
    int n[3];
};

__global__ void sign_weights_kernel(WPtrs wp) {
    int wi = blockIdx.y;
    int n = wp.n[wi];
    const float* s = wp.src[wi];
    float* d = wp.dst[wi];
    for (int i = blockIdx.x * blockDim.x + threadIdx.x; i < n; i += gridDim.x * blockDim.x)
        d[i] = fsign(s[i]);
}

// ---------------- composite stage1 weights ----------------
__global__ void build_wc_kernel(const float* __restrict__ w1, const float* __restrict__ w2,
                                float* __restrict__ wc) {
    int t = threadIdx.x;
    if (t < 208) {
        int co = t / 13, r = t % 13;
        float s = 0.f;
        for (int ci = 0; ci < 16; ++ci)
#pragma unroll
            for (int kh = 0; kh < 5; ++kh) {
                int k5 = r - kh;
                if (k5 >= 0 && k5 < 5)
                    s += fsign(w2[(co * 16 + ci) * 5 + kh]) * fsign(w1[ci * 5 + k5]);
            }
        wc[t] = s;  // exact integer
    }
}

// ---------------- pack conv weights (w3..w10) along Cin into bit words ----------------
struct PW { const float* src; unsigned* dnz; unsigned* dsg; int cout, cin, k, nw; };
struct PWall { PW l[8]; };

__global__ void pack_weights_kernel(PWall pa) {
    PW p = pa.l[blockIdx.y];
    int total = p.cout * p.k * p.nw;
    for (int u = blockIdx.x * blockDim.x + threadIdx.x; u < total; u += gridDim.x * blockDim.x) {
        int co = u / (p.k * p.nw);
        int rem = u % (p.k * p.nw);
        int kk = rem / p.nw, wi = rem % p.nw;
        unsigned nz = 0, sg = 0;
        for (int j = 0; j < 32; ++j) {
            int ci = wi * 32 + j;
            if (ci < p.cin) {
                float v = p.src[(co * p.cin + ci) * p.k + kk];
                if (v != 0.f) nz |= 1u << j;
                if (v < 0.f) sg |= 1u << j;
            }
        }
        p.dnz[u] = nz;
        p.dsg[u] = sg;
    }
}

// ---------------- parallel stats final ----------------
__global__ void stats_finalp(const double* __restrict__ part, int S, long count,
                             float* __restrict__ mean, float* __restrict__ rstd) {
    int c = blockIdx.x, t = threadIdx.x;
    int chunk = (S + 255) / 256;
    int lo = t * chunk, hi = min(S, lo + chunk);
    double s = 0, q = 0;
    for (int i = lo; i < hi; ++i) {
        s += part[((long)c * S + i) * 2];
        q += part[((long)c * S + i) * 2 + 1];
    }
    __shared__ double ls[256], lq[256];
    ls[t] = s; lq[t] = q;
    __syncthreads();
    for (int off = 128; off > 0; off >>= 1) {
        if (t < off) { ls[t] += ls[t + off]; lq[t] += lq[t + off]; }
        __syncthreads();
    }
    if (t == 0) {
        double m = ls[0] / (double)count;
        double v = lq[0] / (double)count - m * m;
        mean[c] = (float)m;
        rstd[c] = (float)(1.0 / sqrt(v + EPSV));
    }
}

// ---------------- BN stats for bn1d (x[n*C + c]) ----------------
__global__ void stats_bn1d(const float* __restrict__ x, int C, int N,
                           float* __restrict__ mean, float* __restrict__ rstd) {
    int c = blockIdx.x;
    double sum = 0, sq = 0;
    for (int n = threadIdx.x; n < N; n += 64) {
        float v = x[(long)n * C + c];
        sum += v;
        sq += (double)v * v;
    }
    for (int off = 32; off > 0; off >>= 1) {
        sum += __shfl_down(sum, off);
        sq += __shfl_down(sq, off);
    }
    if (threadIdx.x == 0) {
        double m = sum / (double)N;
        double v = sq / (double)N - m * m;
        mean[c] = (float)m;
        rstd[c] = (float)(1.0 / sqrt(v + EPSV));
    }
}

// ---------------- stage 1: 13-tap composite conv; LDS-staged store; LDS-reduce stats ----------------
__global__ void stage1_kernel(const float* __restrict__ x, const float* __restrict__ wcg,
                              float* __restrict__ p1, double* __restrict__ part) {
    int n = blockIdx.y;
    int hb = blockIdx.x;
    int ho0 = hb * 28;
    int nrows = min(28, 220 - ho0);
    int nrx = 5 * nrows + 8;
    __shared__ float xs[148 * 9];
    __shared__ float wcl[208];
    __shared__ float st[252 * 17];          // [pos][co], stride 17
    __shared__ double sS[16 * 16], sQ[16 * 16];   // [seg][co]
    int t = threadIdx.x;
    if (t < 208) wcl[t] = wcg[t];
    int hbase = 5 * ho0 - 2;
    for (int i = t; i < nrx * 9; i += 256) {
        int r = i / 9, w = i - r * 9, h = hbase + r;
        xs[i] = (h >= 0 && h < 1100) ? x[(n * 1100 + h) * 9 + w] : 0.f;
    }
    __syncthreads();
    int npos = nrows * 9;
    if (t < npos) {
        int hoL = t / 9, w = t - hoL * 9;
        double xr[13];
        int base = 45 * hoL + w;
#pragma unroll
        for (int r = 0; r < 13; ++r) xr[r] = (double)xs[base + 9 * r];
#pragma unroll
        for (int co = 0; co < 16; ++co) {
            double acc = 0.0;
#pragma unroll
            for (int r = 0; r < 13; ++r)
                acc += (double)wcl[co * 13 + r] * xr[r];
            st[t * 17 + co] = (float)acc;
        }
    }
    __syncthreads();
    // coalesced store
    float4* dst = (float4*)(p1 + (((long)n * 1980 + ho0 * 9) << 4));
    int nf4 = npos * 4;
    for (int u = t; u < nf4; u += 256) {
        int pos = u >> 2, q4 = (u & 3) << 2;
        const float* s4 = &st[pos * 17 + q4];
        dst[u] = make_float4(s4[0], s4[1], s4[2], s4[3]);
    }
    // stats: seg-sliced LDS reduction
    {
        int co = t & 15, seg = t >> 4;
        double s = 0, q = 0;
        for (int pos = seg; pos < npos; pos += 16) {
            double v = (double)st[pos * 17 + co];
            s += v; q += v * v;
        }
        sS[seg * 16 + co] = s;
        sQ[seg * 16 + co] = q;
    }
    __syncthreads();
    if (t < 16) {
        double s = 0, q = 0;
#pragma unroll
        for (int seg = 0; seg < 16; ++seg) {
            s += sS[seg * 16 + t];
            q += sQ[seg * 16 + t];
        }
        long blk = (long)n * 8 + hb;
        part[((long)t * 4096 + blk) * 2] = s;
        part[((long)t * 4096 + blk) * 2 + 1] = q;
    }
}

// ---------------- stage 2: grid(11,512); 180-thread conv3; w3/w4 LDS [kh][co] ----------------
__global__ void stage2_kernel(const float* __restrict__ p1, const float* __restrict__ mean,
    const float* __restrict__ rstd, const float* __restrict__ g, const float* __restrict__ b,
    const float* __restrict__ ap, const unsigned* __restrict__ w3n, const unsigned* __restrict__ w3s,
    const unsigned* __restrict__ w4n, const unsigned* __restrict__ w4s, float* __restrict__ p2,
    double* __restrict__ part) {
    int hb = blockIdx.x;   // 0..10
    int n = blockIdx.y;
    float a = ap[0];
    __shared__ __align__(16) uint2 qx[216];
    __shared__ __align__(16) uint2 ax[180];
    __shared__ __align__(16) uint2 w3L[160];   // [kh*32+co]
    __shared__ __align__(16) uint2 w4L[160];   // [kh*32+co]
    __shared__ float sArr[1152];
    int t = threadIdx.x;
    if (t < 160) {
        int kh = t / 32, co = t % 32;
        w3L[t] = make_uint2(w3n[co * 5 + kh], w3s[co * 5 + kh]);
        w4L[t] = make_uint2(w4n[co * 5 + kh], w4s[co * 5 + kh]);
    }
    if (t < 216) {
        int rl = t / 9, w = t % 9;
        int r = 20 * hb - 2 + rl;
        unsigned nz = 0, sg = 0;
        if (r >= 0 && r < 220) {
            const float4* src = (const float4*)(p1 + (((long)n * 1980 + r * 9 + w) << 4));
            float4 v4[4];
#pragma unroll
            for (int q4 = 0; q4 < 4; ++q4) v4[q4] = src[q4];
            const float* vals = (const float*)v4;
#pragma unroll
            for (int ci = 0; ci < 16; ++ci) {
                float bnv = (vals[ci] - mean[ci]) * rstd[ci] * g[ci] + b[ci];
                float pr = bnv < 0.f ? a * bnv : bnv;
                if (pr != 0.f) { nz |= 1u << ci; if (pr < 0.f) sg |= 1u << ci; }
            }
        }
        qx[t] = make_uint2(nz, sg);
    }
    __syncthreads();
    // conv3: 180 threads, one row each
    if (t < 180) {
        int jl = t / 9, w = t % 9;
        uint2 xv[5];
#pragma unroll
        for (int kh = 0; kh < 5; ++kh) xv[kh] = qx[(jl + kh) * 9 + w];
        unsigned onz = 0, osg = 0;
        for (int co = 0; co < 32; co += 2) {
            int c0 = 0, n0 = 0, c1 = 0, n1 = 0;
#pragma unroll
            for (int kh = 0; kh < 5; ++kh) {
                const uint4 wv = *(const uint4*)&w3L[kh * 32 + co];
                unsigned b0 = xv[kh].x & wv.x;
                c0 += __popc(b0);
                n0 += __popc((xv[kh].y ^ wv.y) & b0);
                unsigned b1 = xv[kh].x & wv.z;
                c1 += __popc(b1);
                n1 += __popc((xv[kh].y ^ wv.w) & b1);
            }
            int s0 = c0 - 2 * n0, s1 = c1 - 2 * n1;
            if (s0 != 0) { onz |= 1u << co; if (s0 < 0) osg |= 1u << co; }
            if (s1 != 0) { onz |= 1u << (co + 1); if (s1 < 0) osg |= 1u << (co + 1); }
        }
        ax[t] = make_uint2(onz, osg);
    }
    __syncthreads();
    // conv4: o = pos*32+co
    for (int o = t; o < 1152; o += 256) {
        int pos = o >> 5, co = o & 31;
        int hol = pos / 9, w = pos % 9;
        int cnt = 0, neg = 0;
#pragma unroll
        for (int kh = 0; kh < 5; ++kh) {
            uint2 av = ax[(5 * hol + kh) * 9 + w];
            uint2 wv = w4L[kh * 32 + co];
            unsigned both = av.x & wv.x;
            cnt += __popc(both);
            neg += __popc((av.y ^ wv.y) & both);
        }
        float val = (float)(cnt - 2 * neg);
        sArr[o] = val;
        p2[(((long)n * 396 + (4 * hb + hol) * 9 + w) << 5) + co] = val;
    }
    __syncthreads();
    if (t < 32) {
        double s = 0, q = 0;
        for (int pos = 0; pos < 36; ++pos) {
            double v = (double)sArr[pos * 32 + t];
            s += v; q += v * v;
        }
        long blk = (long)hb * 512 + n;
        part[((long)t * 5632 + blk) * 2] = s;
        part[((long)t * 5632 + blk) * 2 + 1] = q;
    }
}

// ---------------- stage 3: grid(4,512); 198-thread conv5; w6 [kh][co] (round-13 proven) ----------------
__global__ void stage3_kernel(const float* __restrict__ p2, const float* __restrict__ mean,
    const float* __restrict__ rstd, const float* __restrict__ g, const float* __restrict__ b,
    const float* __restrict__ ap, const unsigned* __restrict__ w5n, const unsigned* __restrict__ w5s,
    const unsigned* __restrict__ w6n, const unsigned* __restrict__ w6s, float* __restrict__ p3,
    double* __restrict__ part) {
    int ho = blockIdx.x;   // 0..3
    int n = blockIdx.y;
    float a = ap[0];
    __shared__ __align__(16) uint2 qx[189];
    __shared__ __align__(16) uint2 ax[99 * 2];
    __shared__ __align__(16) uint2 w5L[704];     // [kh*64+co]
    __shared__ __align__(16) uint2 w6L[1408];    // [(kh*64+co)*2+wi]
    __shared__ float sArr[576];
    int t = threadIdx.x;
    for (int i = t; i < 704; i += 256) {
        int kh = i / 64, co = i % 64;
        w5L[i] = make_uint2(w5n[co * 11 + kh], w5s[co * 11 + kh]);
    }
    for (int i = t; i < 1408; i += 256) {
        int pair = i >> 1, wi = i & 1;
        int kh = pair / 64, co = pair % 64;
        w6L[i] = make_uint2(w6n[(co * 11 + kh) * 2 + wi], w6s[(co * 11 + kh) * 2 + wi]);
    }
    if (t < 189) {
        int rl = t / 9, w = t % 9;
        int r = 11 * ho - 5 + rl;
        unsigned nz = 0, sg = 0;
        if (r >= 0 && r < 44) {
            const float4* src = (const float4*)(p2 + (((long)n * 396 + r * 9 + w) << 5));
            float4 v4[8];
#pragma unroll
            for (int q4 = 0; q4 < 8; ++q4) v4[q4] = src[q4];
            const float* vals = (const float*)v4;
#pragma unroll
            for (int ci = 0; ci < 32; ++ci) {
                float bnv = (vals[ci] - mean[ci]) * rstd[ci] * g[ci] + b[ci];
                float pr = bnv < 0.f ? a * bnv : bnv;
                if (pr != 0.f) { nz |= 1u << ci; if (pr < 0.f) sg |= 1u << ci; }
            }
        }
        qx[t] = make_uint2(nz, sg);
    }
    __syncthreads();
    // conv5: unit = (p, wi); 198 threads
    if (t < 198) {
        int p = t >> 1, wi = t & 1;
        int jl = p / 9, w = p % 9;
        uint2 xv[11];
#pragma unroll
        for (int kh = 0; kh < 11; ++kh) xv[kh] = qx[(jl + kh) * 9 + w];
        unsigned onz = 0, osg = 0;
        for (int jj = 0; jj < 32; jj += 2) {
            int co0 = wi * 32 + jj;
            int c0 = 0, n0 = 0, c1 = 0, n1 = 0;
#pragma unroll
            for (int kh = 0; kh < 11; ++kh) {
                const uint4 wv = *(const uint4*)&w5L[kh * 64 + co0];
                unsigned b0 = xv[kh].x & wv.x;
                c0 += __popc(b0);
                n0 += __popc((xv[kh].y ^ wv.y) & b0);
                unsigned b1 = xv[kh].x & wv.z;
                c1 += __popc(b1);
                n1 += __popc((xv[kh].y ^ wv.w) & b1);
            }
            int s0 = c0 - 2 * n0, s1 = c1 - 2 * n1;
            if (s0 != 0) { onz |= 1u << jj; if (s0 < 0) osg |= 1u << jj; }
            if (s1 != 0) { onz |= 1u << (jj + 1); if (s1 < 0) osg |= 1u << (jj + 1); }
        }
        ax[p * 2 + wi] = make_uint2(onz, osg);
    }
    __syncthreads();
    // conv6: o = w*64+co
    for (int o = t; o < 576; o += 256) {
        int co = o & 63, w = o >> 6;
        int cA = 0, nA = 0, cB = 0, nB = 0;
        for (int kh = 0; kh < 11; ++kh) {
            const uint4 av = *(const uint4*)&ax[(kh * 9 + w) * 2];
            const uint4 wv = *(const uint4*)&w6L[(kh * 64 + co) * 2];
            unsigned b0 = av.x & wv.x;
            cA += __popc(b0);
            nA += __popc((av.y ^ wv.y) & b0);
            unsigned b1 = av.z & wv.z;
            cB += __popc(b1);
            nB += __popc((av.w ^ wv.w) & b1);
        }
        float val = (float)((cA + cB) - 2 * (nA + nB));
        sArr[o] = val;
        p3[(((long)n * 36 + ho * 9 + w) << 6) + co] = val;
    }
    __syncthreads();
    if (t < 64) {
        double s = 0, q = 0;
        for (int w = 0; w < 9; ++w) {
            double v = (double)sArr[w * 64 + t];
            s += v; q += v * v;
        }
        long blk = (long)ho * 512 + n;
        part[((long)t * 2048 + blk) * 2] = s;
        part[((long)t * 2048 + blk) * 2 + 1] = q;
    }
}

// ---------------- stage 4: grid(4,512) ----------------
__global__ void stage4_kernel(const float* __restrict__ p3, const float* __restrict__ mean,
    const float* __restrict__ rstd, const float* __restrict__ g, const float* __restrict__ b,
    const float* __restrict__ ap, const unsigned* __restrict__ w7n, const unsigned* __restrict__ w7s,
    const unsigned* __restrict__ w8n, const unsigned* __restrict__ w8s, float* __restrict__ p4,
    double* __restrict__ part) {
    int h = blockIdx.x;   // 0..3
    int n = blockIdx.y;
    float a = ap[0];
    __shared__ unsigned q[9 * 4];
    __shared__ signed char strit[9 * 128];
    __shared__ unsigned an[9 * 4], ag[9 * 4];
    __shared__ float sArr[384];
    int t = threadIdx.x;
    if (t < 18) {
        int w = t >> 1, half = t & 1;
        const float4* src = (const float4*)(p3 + (((long)n * 36 + h * 9 + w) << 6) + half * 32);
        float4 v4[8];
#pragma unroll
        for (int q4 = 0; q4 < 8; ++q4) v4[q4] = src[q4];
        const float* vals = (const float*)v4;
        unsigned nz = 0, sg = 0;
#pragma unroll
        for (int j = 0; j < 32; ++j) {
            int ci = half * 32 + j;
            float bnv = (vals[j] - mean[ci]) * rstd[ci] * g[ci] + b[ci];
            float pr = bnv < 0.f ? a * bnv : bnv;
            if (pr != 0.f) { nz |= 1u << j; if (pr < 0.f) sg |= 1u << j; }
        }
        q[w * 4 + half] = nz; q[w * 4 + 2 + half] = sg;
    }
    __syncthreads();
    for (int o = t; o < 1152; o += 256) {
        int w = o / 128, co = o % 128;
        int cnt = 0, neg = 0;
        for (int kw = 0; kw < 3; ++kw) {
            int wl = w + kw - 1;
            if (wl < 0 || wl >= 9) continue;
#pragma unroll
            for (int iw = 0; iw < 2; ++iw) {
                unsigned both = q[wl * 4 + iw] & w7n[(co * 3 + kw) * 2 + iw];
                cnt += __popc(both);
                neg += __popc((q[wl * 4 + 2 + iw] ^ w7s[(co * 3 + kw) * 2 + iw]) & both);
            }
        }
        int s = cnt - 2 * neg;
        strit[o] = (signed char)((s > 0) - (s < 0));
    }
    __syncthreads();
    if (t < 36) {
        int w = t >> 2, wi = t & 3;
        unsigned nz = 0, sg = 0;
        for (int j = 0; j < 32; ++j) {
            int tr = strit[w * 128 + wi * 32 + j];
            if (tr) { nz |= 1u << j; if (tr < 0) sg |= 1u << j; }
        }
        an[w * 4 + wi] = nz; ag[w * 4 + wi] = sg;
    }
    __syncthreads();
    for (int o = t; o < 384; o += 256) {
        int wo = o >> 7, co = o & 127;
        int cnt = 0, neg = 0;
        for (int kw = 0; kw < 3; ++kw) {
            int wl = 3 * wo + kw;
#pragma unroll
            for (int iw = 0; iw < 4; ++iw) {
                unsigned both = an[wl * 4 + iw] & w8n[(co * 3 + kw) * 4 + iw];
                cnt += __popc(both);
                neg += __popc((ag[wl * 4 + iw] ^ w8s[(co * 3 + kw) * 4 + iw]) & both);
            }
        }
        float val = (float)(cnt - 2 * neg);
        sArr[o] = val;
        p4[(((long)n * 12 + h * 3 + wo) << 7) + co] = val;
    }
    __syncthreads();
    if (t < 128) {
        double s = 0, qd = 0;
        for (int wo = 0; wo < 3; ++wo) {
            double v = (double)sArr[wo * 128 + t];
            s += v; qd += v * v;
        }
        long blk = (long)h * 512 + n;
        part[((long)t * 2048 + blk) * 2] = s;
        part[((long)t * 2048 + blk) * 2 + 1] = qd;
    }
}

// ---------------- stage 5: grid(4,512) ----------------
__global__ void stage5_kernel(const float* __restrict__ p4, const float* __restrict__ mean,
    const float* __restrict__ rstd, const float* __restrict__ g, const float* __restrict__ b,
    const float* __restrict__ ap, const unsigned* __restrict__ w9n, const unsigned* __restrict__ w9s,
    const unsigned* __restrict__ w10n, const unsigned* __restrict__ w10s, float* __restrict__ p5,
    double* __restrict__ part) {
    int h = blockIdx.x;   // 0..3
    int n = blockIdx.y;
    float a = ap[0];
    __shared__ unsigned q[3 * 8];
    __shared__ signed char strit[3 * 256];
    __shared__ unsigned an[3 * 8], ag[3 * 8];
    int t = threadIdx.x;
    if (t < 12) {
        int w = t >> 2, wq = t & 3;
        const float4* src = (const float4*)(p4 + (((long)n * 12 + h * 3 + w) << 7) + wq * 32);
        float4 v4[8];
#pragma unroll
        for (int q4 = 0; q4 < 8; ++q4) v4[q4] = src[q4];
        const float* vals = (const float*)v4;
        unsigned nz = 0, sg = 0;
#pragma unroll
        for (int j = 0; j < 32; ++j) {
            int ci = wq * 32 + j;
            float bnv = (vals[j] - mean[ci]) * rstd[ci] * g[ci] + b[ci];
            float pr = bnv < 0.f ? a * bnv : bnv;
            if (pr != 0.f) { nz |= 1u << j; if (pr < 0.f) sg |= 1u << j; }
        }
        q[w * 8 + wq] = nz; q[w * 8 + 4 + wq] = sg;
    }
    __syncthreads();
    for (int o = t; o < 768; o += 256) {
        int w = o / 256, co = o % 256;
        int cnt = 0, neg = 0;
        for (int kw = 0; kw < 3; ++kw) {
            int wl = w + kw - 1;
            if (wl < 0 || wl >= 3) continue;
#pragma unroll
            for (int iw = 0; iw < 4; ++iw) {
                unsigned both = q[wl * 8 + iw] & w9n[(co * 3 + kw) * 4 + iw];
                cnt += __popc(both);
                neg += __popc((q[wl * 8 + 4 + iw] ^ w9s[(co * 3 + kw) * 4 + iw]) & both);
            }
        }
        int s = cnt - 2 * neg;
        strit[o] = (signed char)((s > 0) - (s < 0));
    }
    __syncthreads();
    if (t < 24) {
        int w = t >> 3, wi = t & 7;
        unsigned nz = 0, sg = 0;
        for (int j = 0; j < 32; ++j) {
            int tr = strit[w * 256 + wi * 32 + j];
            if (tr) { nz |= 1u << j; if (tr < 0) sg |= 1u << j; }
        }
        an[w * 8 + wi] = nz; ag[w * 8 + wi] = sg;
    }
    __syncthreads();
    if (t < 256) {
        int co = t;
        int cnt = 0, neg = 0;
        for (int kw = 0; kw < 3; ++kw) {
#pragma unroll
            for (int iw = 0; iw < 8; ++iw) {
                unsigned both = an[kw * 8 + iw] & w10n[(co * 3 + kw) * 8 + iw];
                cnt += __popc(both);
                neg += __popc((ag[kw * 8 + iw] ^ w10s[(co * 3 + kw) * 8 + iw]) & both);
            }
        }
        float val = (float)(cnt - 2 * neg);
        p5[(long)n * 1024 + co * 4 + h] = val;
        long blk = (long)h * 512 + n;
        double v = (double)val;
        part[((long)co * 2048 + blk) * 2] = v;
        part[((long)co * 2048 + blk) * 2 + 1] = v * v;
    }
}

// ---------------- fc1: grid(64); 8 samples per block, sfc1 streamed once (L2-warm reuse) ----------------
__global__ void fc1_kernel(const float* __restrict__ p5, const float* __restrict__ mean,
                           const float* __restrict__ rstd, const float* __restrict__ g,
                           const float* __restrict__ b, const float* __restrict__ ap,
                           const float* __restrict__ sfc1, float* __restrict__ h1) {
    int n0 = blockIdx.x * 8;
    float a = ap[0];
    __shared__ float hv[1024];
    int t = threadIdx.x;
    int wave = t >> 6, lane = t & 63;
    for (int dn = 0; dn < 8; ++dn) {
        int n = n0 + dn;
        for (int idx = t; idx < 1024; idx += 256) {
            int c = idx >> 2;
            float v = p5[(long)n * 1024 + idx];
            float bnv = (v - mean[c]) * rstd[c] * g[c] + b[c];
            hv[idx] = bnv < 0.f ? a * bnv : bnv;
        }
        __syncthreads();
        float hr[16];
#pragma unroll
        for (int m = 0; m < 16; ++m) hr[m] = hv[lane * 16 + m];
        for (int jj = 0; jj < 64; ++jj) {
            int j = wave * 64 + jj;
            const float4* wr = (const float4*)(sfc1 + (j << 10) + (lane << 4));
            double s = 0.0;
#pragma unroll
            for (int q4 = 0; q4 < 4; ++q4) {
                float4 wv = wr[q4];
                s += (double)(hr[q4 * 4 + 0] * wv.x);
                s += (double)(hr[q4 * 4 + 1] * wv.y);
                s += (double)(hr[q4 * 4 + 2] * wv.z);
                s += (double)(hr[q4 * 4 + 3] * wv.w);
            }
#pragma unroll
            for (int off = 32; off > 0; off >>= 1) s += __shfl_down(s, off, 64);
            if (lane == 0) h1[(long)n * 256 + j] = (float)s;
        }
        __syncthreads();
    }
}

// ---------------- fc2 ----------------
__global__ void fc2_kernel(const float* __restrict__ h1, const float* __restrict__ mean,
                           const float* __restrict__ rstd, const float* __restrict__ g,
                           const float* __restrict__ b, const float* __restrict__ ap,
                           const float* __restrict__ sfc2, float* __restrict__ h2) {
    int n = blockIdx.x;
    float a = ap[0];
    __shared__ float sv[256];
    int t = threadIdx.x;
    if (t < 256) {
        float v = h1[n * 256 + t];
        float bnv = (v - mean[t]) * rstd[t] * g[t] + b[t];
        float pr = bnv < 0.f ? a * bnv : bnv;
        sv[t] = fsign(pr);
    }
    __syncthreads();
    if (t < 64) {
        float s = 0.f;
        for (int k = 0; k < 256; ++k) s += sv[k] * sfc2[t * 256 + k];
        h2[n * 64 + t] = s;
    }
}

// ---------------- fc3 ----------------
__global__ void fc3_kernel(const float* __restrict__ h2, const float* __restrict__ mean,
                           const float* __restrict__ rstd, const float* __restrict__ g,
                           const float* __restrict__ b, const float* __restrict__ ap,
                           const float* __restrict__ sfc3, float* __restrict__ out) {
    int n = blockIdx.x;
    float a = ap[0];
    __shared__ float sv[64];
    int t = threadIdx.x;
    if (t < 64) {
        float v = h2[n * 64 + t];
        float bnv = (v - mean[t]) * rstd[t] * g[t] + b[t];
        float pr = bnv < 0.f ? a * bnv : bnv;
        sv[t] = fsign(pr);
    }
    __syncthreads();
    if (t < 2) {
        float s = 0.f;
        for (int k = 0; k < 64; ++k) s += sv[k] * sfc3[t * 64 + k];
        out[n * 2 + t] = s;
    }
}

extern "C" void kernel_launch(void* const* d_in, const int* in_sizes, int n_in,
                              void* d_out, int out_size, void* d_ws, size_t ws_size,
                              hipStream_t stream) {
    const float* x = (const float*)d_in[0];
    const float* G[8] = {nullptr, (const float*)d_in[11], (const float*)d_in[14],
                         (const float*)d_in[17], (const float*)d_in[20], (const float*)d_in[23],
                         (const float*)d_in[29], (const float*)d_in[31]};
    const float* B[8] = {nullptr, (const float*)d_in[12], (const float*)d_in[15],
                         (const float*)d_in[18], (const float*)d_in[21], (const float*)d_in[24],
                         (const float*)d_in[30], (const float*)d_in[32]};
    const float* A[8] = {nullptr, (const float*)d_in[13], (const float*)d_in[16],
                         (const float*)d_in[19], (const float*)d_in[22], (const float*)d_in[25],
                         (const float*)d_in[33], (const float*)d_in[34]};

    float* ws = (float*)d_ws;
    size_t off = 0;
    const int fsz[3] = {262144, 16384, 128};
    float* fw[3];
    for (int i = 0; i < 3; ++i) { fw[i] = ws + off; off += (size_t)fsz[i]; }
    float* sfc1 = fw[0]; float* sfc2 = fw[1]; float* sfc3 = fw[2];
    float* wc = ws + off; off += 208;

    const int psz[8] = {160, 160, 704, 1408, 768, 1536, 3072, 6144};
    unsigned* pn[8]; unsigned* pg[8];
    for (int i = 0; i < 8; ++i) {
        pn[i] = (unsigned*)(ws + off); off += (size_t)psz[i];
        pg[i] = (unsigned*)(ws + off); off += (size_t)psz[i];
    }

    float* p1 = ws + off; off += 16220160;   // (n,1980,16)
    float* p2 = ws + off; off += 6488064;    // (n,396,32)
    float* p3 = ws + off; off += 1179648;    // (n,36,64)
    float* p4 = ws + off; off += 786432;     // (n,12,128)
    float* p5 = ws + off; off += 524288;     // (n,1024)
    float* h1 = ws + off; off += 131072;
    float* h2 = ws + off; off += 32768;
    float* mean1 = ws + off; off += 16;  float* rstd1 = ws + off; off += 16;
    float* mean2 = ws + off; off += 32;  float* rstd2 = ws + off; off += 32;
    float* mean3 = ws + off; off += 64;  float* rstd3 = ws + off; off += 64;
    float* mean4 = ws + off; off += 128; float* rstd4 = ws + off; off += 128;
    float* mean5 = ws + off; off += 256; float* rstd5 = ws + off; off += 256;
    float* mean6 = ws + off; off += 256; float* rstd6 = ws + off; off += 256;
    float* mean7 = ws + off; off += 64;  float* rstd7 = ws + off; off += 64;
    if (off & 1) off += 1;  // 8B-align
    double* part = (double*)(ws + off); off += 2 * 1048576;

    // 1. sign fc weights + composite stage1 weights
    WPtrs wp;
    const int fsrc_idx[3] = {26, 27, 28};
    for (int i = 0; i < 3; ++i) {
        wp.src[i] = (const float*)d_in[fsrc_idx[i]];
        wp.dst[i] = fw[i];
        wp.n[i] = fsz[i];
    }
    hipLaunchKernelGGL(sign_weights_kernel, dim3(32, 3), dim3(256), 0, stream, wp);
    hipLaunchKernelGGL(build_wc_kernel, dim3(1), dim3(256), 0, stream,
                       (const float*)d_in[1], (const float*)d_in[2], wc);

    // 2. pack conv weights w3..w10
    PWall pa;
    const int cout_[8] = {32, 32, 64, 64, 128, 128, 256, 256};
    const int cin_[8]  = {16, 32, 32, 64, 64, 128, 128, 256};
    const int kk_[8]   = {5, 5, 11, 11, 3, 3, 3, 3};
    for (int i = 0; i < 8; ++i) {
        pa.l[i].src = (const float*)d_in[3 + i];
        pa.l[i].dnz = pn[i];
        pa.l[i].dsg = pg[i];
        pa.l[i].cout = cout_[i];
        pa.l[i].cin = cin_[i];
        pa.l[i].k = kk_[i];
        pa.l[i].nw = (cin_[i] + 31) / 32;
    }
    hipLaunchKernelGGL(pack_weights_kernel, dim3(4, 8), dim3(256), 0, stream, pa);

    // 3. stage1 -> p1t + partials; finalize bn1
    hipLaunchKernelGGL(stage1_kernel, dim3(8, 512), dim3(256), 0, stream, x, wc, p1, part);
    hipLaunchKernelGGL(stats_finalp, dim3(16), dim3(256), 0, stream, part, 4096,
                       (long)512 * 1980, mean1, rstd1);

    // 4. stage2 -> p2t + partials; finalize bn2
    hipLaunchKernelGGL(stage2_kernel, dim3(11, 512), dim3(256), 0, stream, p1, mean1, rstd1,
                       G[1], B[1], A[1], pn[0], pg[0], pn[1], pg[1], p2, part);
    hipLaunchKernelGGL(stats_finalp, dim3(32), dim3(256), 0, stream, part, 5632,
                       (long)512 * 396, mean2, rstd2);

    // 5. stage3 -> p3t + partials; finalize bn3
    hipLaunchKernelGGL(stage3_kernel, dim3(4, 512), dim3(256), 0, stream, p2, mean2, rstd2,
                       G[2], B[2], A[2], pn[2], pg[2], pn[3], pg[3], p3, part);
    hipLaunchKernelGGL(stats_finalp, dim3(64), dim3(256), 0, stream, part, 2048,
                       (long)512 * 36, mean3, rstd3);

    // 6. stage4 -> p4t + partials; finalize bn4
    hipLaunchKernelGGL(stage4_kernel, dim3(4, 512), dim3(256), 0, stream, p3, mean3, rstd3,
                       G[3], B[3], A[3], pn[4], pg[4], pn[5], pg[5], p4, part);
    hipLaunchKernelGGL(stats_finalp, dim3(128), dim3(256), 0, stream, part, 2048,
                       (long)512 * 12, mean4, rstd4);

    // 7. stage5 -> p5 + partials; finalize bn5
    hipLaunchKernelGGL(stage5_kernel, dim3(4, 512), dim3(256), 0, stream, p4, mean4, rstd4,
                       G[4], B[4], A[4], pn[6], pg[6], pn[7], pg[7], p5, part);
    hipLaunchKernelGGL(stats_finalp, dim3(256), dim3(256), 0, stream, part, 2048,
                       (long)512 * 4, mean5, rstd5);

    // 8. fc1 (8 samples/block) -> h1, stats
    hipLaunchKernelGGL(fc1_kernel, dim3(64), dim3(256), 0, stream, p5, mean5, rstd5,
                       G[5], B[5], A[5], sfc1, h1);
    hipLaunchKernelGGL(stats_bn1d, dim3(256), dim3(64), 0, stream, h1, 256, 512, mean6, rstd6);

    // 9. fc2 -> h2, stats
    hipLaunchKernelGGL(fc2_kernel, dim3(512), dim3(256), 0, stream, h1, mean6, rstd6,
                       G[6], B[6], A[6], sfc2, h2);
    hipLaunchKernelGGL(stats_bn1d, dim3(64), dim3(64), 0, stream, h2, 64, 512, mean7, rstd7);

    // 10. fc3 -> d_out
    hipLaunchKernelGGL(fc3_kernel, dim3(512), dim3(256), 0, stream, h2, mean7, rstd7,
                       G[7], B[7], A[7], sfc3, (float*)d_out);
}

// Round 17
// 299.190 us; speedup vs baseline: 1.7441x; 1.7441x over previous
//
#include <hip/hip_runtime.h>
#include <hip/hip_bf16.h>

#define EPSV 1e-5

__device__ __forceinline__ float fsign(float x) {
    return (float)((x > 0.f) - (x < 0.f));
}

// ---------------- sign(weights) for fc1, fc2, fc3 ----------------
struct WPtrs {
    const float* src[3];
    float* dst[3];
    int n[3];
};

__global__ void sign_weights_kernel(WPtrs wp) {
    int wi = blockIdx.y;
    int n = wp.n[wi];
    const float* s = wp.src[wi];
    float* d = wp.dst[wi];
    for (int i = blockIdx.x * blockDim.x + threadIdx.x; i < n; i += gridDim.x * blockDim.x)
        d[i] = fsign(s[i]);
}

// ---------------- composite stage1 weights ----------------
__global__ void build_wc_kernel(const float* __restrict__ w1, const float* __restrict__ w2,
                                float* __restrict__ wc) {
    int t = threadIdx.x;
    if (t < 208) {
        int co = t / 13, r = t % 13;
        float s = 0.f;
        for (int ci = 0; ci < 16; ++ci)
#pragma unroll
            for (int kh = 0; kh < 5; ++kh) {
                int k5 = r - kh;
                if (k5 >= 0 && k5 < 5)
                    s += fsign(w2[(co * 16 + ci) * 5 + kh]) * fsign(w1[ci * 5 + k5]);
            }
        wc[t] = s;  // exact integer
    }
}

// ---------------- pack conv weights (w3..w10) along Cin into bit words ----------------
struct PW { const float* src; unsigned* dnz; unsigned* dsg; int cout, cin, k, nw; };
struct PWall { PW l[8]; };

__global__ void pack_weights_kernel(PWall pa) {
    PW p = pa.l[blockIdx.y];
    int total = p.cout * p.k * p.nw;
    for (int u = blockIdx.x * blockDim.x + threadIdx.x; u < total; u += gridDim.x * blockDim.x) {
        int co = u / (p.k * p.nw);
        int rem = u % (p.k * p.nw);
        int kk = rem / p.nw, wi = rem % p.nw;
        unsigned nz = 0, sg = 0;
        for (int j = 0; j < 32; ++j) {
            int ci = wi * 32 + j;
            if (ci < p.cin) {
                float v = p.src[(co * p.cin + ci) * p.k + kk];
                if (v != 0.f) nz |= 1u << j;
                if (v < 0.f) sg |= 1u << j;
            }
        }
        p.dnz[u] = nz;
        p.dsg[u] = sg;
    }
}

// ---------------- parallel stats final ----------------
__global__ void stats_finalp(const double* __restrict__ part, int S, long count,
                             float* __restrict__ mean, float* __restrict__ rstd) {
    int c = blockIdx.x, t = threadIdx.x;
    int chunk = (S + 255) / 256;
    int lo = t * chunk, hi = min(S, lo + chunk);
    double s = 0, q = 0;
    for (int i = lo; i < hi; ++i) {
        s += part[((long)c * S + i) * 2];
        q += part[((long)c * S + i) * 2 + 1];
    }
    __shared__ double ls[256], lq[256];
    ls[t] = s; lq[t] = q;
    __syncthreads();
    for (int off = 128; off > 0; off >>= 1) {
        if (t < off) { ls[t] += ls[t + off]; lq[t] += lq[t + off]; }
        __syncthreads();
    }
    if (t == 0) {
        double m = ls[0] / (double)count;
        double v = lq[0] / (double)count - m * m;
        mean[c] = (float)m;
        rstd[c] = (float)(1.0 / sqrt(v + EPSV));
    }
}

// ---------------- BN stats for bn1d (x[n*C + c]) ----------------
__global__ void stats_bn1d(const float* __restrict__ x, int C, int N,
                           float* __restrict__ mean, float* __restrict__ rstd) {
    int c = blockIdx.x;
    double sum = 0, sq = 0;
    for (int n = threadIdx.x; n < N; n += 64) {
        float v = x[(long)n * C + c];
        sum += v;
        sq += (double)v * v;
    }
    for (int off = 32; off > 0; off >>= 1) {
        sum += __shfl_down(sum, off);
        sq += __shfl_down(sq, off);
    }
    if (threadIdx.x == 0) {
        double m = sum / (double)N;
        double v = sq / (double)N - m * m;
        mean[c] = (float)m;
        rstd[c] = (float)(1.0 / sqrt(v + EPSV));
    }
}

// ---------------- stage 1: 13-tap composite conv; LDS-staged store; LDS-reduce stats ----------------
__global__ void stage1_kernel(const float* __restrict__ x, const float* __restrict__ wcg,
                              float* __restrict__ p1, double* __restrict__ part) {
    int n = blockIdx.y;
    int hb = blockIdx.x;
    int ho0 = hb * 28;
    int nrows = min(28, 220 - ho0);
    int nrx = 5 * nrows + 8;
    __shared__ float xs[148 * 9];
    __shared__ float wcl[208];
    __shared__ float st[252 * 17];          // [pos][co], stride 17
    __shared__ double sS[16 * 16], sQ[16 * 16];   // [seg][co]
    int t = threadIdx.x;
    if (t < 208) wcl[t] = wcg[t];
    int hbase = 5 * ho0 - 2;
    for (int i = t; i < nrx * 9; i += 256) {
        int r = i / 9, w = i - r * 9, h = hbase + r;
        xs[i] = (h >= 0 && h < 1100) ? x[(n * 1100 + h) * 9 + w] : 0.f;
    }
    __syncthreads();
    int npos = nrows * 9;
    if (t < npos) {
        int hoL = t / 9, w = t - hoL * 9;
        double xr[13];
        int base = 45 * hoL + w;
#pragma unroll
        for (int r = 0; r < 13; ++r) xr[r] = (double)xs[base + 9 * r];
#pragma unroll
        for (int co = 0; co < 16; ++co) {
            double acc = 0.0;
#pragma unroll
            for (int r = 0; r < 13; ++r)
                acc += (double)wcl[co * 13 + r] * xr[r];
            st[t * 17 + co] = (float)acc;
        }
    }
    __syncthreads();
    // coalesced store
    float4* dst = (float4*)(p1 + (((long)n * 1980 + ho0 * 9) << 4));
    int nf4 = npos * 4;
    for (int u = t; u < nf4; u += 256) {
        int pos = u >> 2, q4 = (u & 3) << 2;
        const float* s4 = &st[pos * 17 + q4];
        dst[u] = make_float4(s4[0], s4[1], s4[2], s4[3]);
    }
    // stats: seg-sliced LDS reduction
    {
        int co = t & 15, seg = t >> 4;
        double s = 0, q = 0;
        for (int pos = seg; pos < npos; pos += 16) {
            double v = (double)st[pos * 17 + co];
            s += v; q += v * v;
        }
        sS[seg * 16 + co] = s;
        sQ[seg * 16 + co] = q;
    }
    __syncthreads();
    if (t < 16) {
        double s = 0, q = 0;
#pragma unroll
        for (int seg = 0; seg < 16; ++seg) {
            s += sS[seg * 16 + t];
            q += sQ[seg * 16 + t];
        }
        long blk = (long)n * 8 + hb;
        part[((long)t * 4096 + blk) * 2] = s;
        part[((long)t * 4096 + blk) * 2 + 1] = q;
    }
}

// ---------------- stage 2: grid(11,512); 180-thread conv3; w3/w4 LDS [kh][co] ----------------
__global__ void stage2_kernel(const float* __restrict__ p1, const float* __restrict__ mean,
    const float* __restrict__ rstd, const float* __restrict__ g, const float* __restrict__ b,
    const float* __restrict__ ap, const unsigned* __restrict__ w3n, const unsigned* __restrict__ w3s,
    const unsigned* __restrict__ w4n, const unsigned* __restrict__ w4s, float* __restrict__ p2,
    double* __restrict__ part) {
    int hb = blockIdx.x;   // 0..10
    int n = blockIdx.y;
    float a = ap[0];
    __shared__ __align__(16) uint2 qx[216];
    __shared__ __align__(16) uint2 ax[180];
    __shared__ __align__(16) uint2 w3L[160];   // [kh*32+co]
    __shared__ __align__(16) uint2 w4L[160];   // [kh*32+co]
    __shared__ float sArr[1152];
    int t = threadIdx.x;
    if (t < 160) {
        int kh = t / 32, co = t % 32;
        w3L[t] = make_uint2(w3n[co * 5 + kh], w3s[co * 5 + kh]);
        w4L[t] = make_uint2(w4n[co * 5 + kh], w4s[co * 5 + kh]);
    }
    if (t < 216) {
        int rl = t / 9, w = t % 9;
        int r = 20 * hb - 2 + rl;
        unsigned nz = 0, sg = 0;
        if (r >= 0 && r < 220) {
            const float4* src = (const float4*)(p1 + (((long)n * 1980 + r * 9 + w) << 4));
            float4 v4[4];
#pragma unroll
            for (int q4 = 0; q4 < 4; ++q4) v4[q4] = src[q4];
            const float* vals = (const float*)v4;
#pragma unroll
            for (int ci = 0; ci < 16; ++ci) {
                float bnv = (vals[ci] - mean[ci]) * rstd[ci] * g[ci] + b[ci];
                float pr = bnv < 0.f ? a * bnv : bnv;
                if (pr != 0.f) { nz |= 1u << ci; if (pr < 0.f) sg |= 1u << ci; }
            }
        }
        qx[t] = make_uint2(nz, sg);
    }
    __syncthreads();
    // conv3: 180 threads, one row each
    if (t < 180) {
        int jl = t / 9, w = t % 9;
        uint2 xv[5];
#pragma unroll
        for (int kh = 0; kh < 5; ++kh) xv[kh] = qx[(jl + kh) * 9 + w];
        unsigned onz = 0, osg = 0;
        for (int co = 0; co < 32; co += 2) {
            int c0 = 0, n0 = 0, c1 = 0, n1 = 0;
#pragma unroll
            for (int kh = 0; kh < 5; ++kh) {
                const uint4 wv = *(const uint4*)&w3L[kh * 32 + co];
                unsigned b0 = xv[kh].x & wv.x;
                c0 += __popc(b0);
                n0 += __popc((xv[kh].y ^ wv.y) & b0);
                unsigned b1 = xv[kh].x & wv.z;
                c1 += __popc(b1);
                n1 += __popc((xv[kh].y ^ wv.w) & b1);
            }
            int s0 = c0 - 2 * n0, s1 = c1 - 2 * n1;
            if (s0 != 0) { onz |= 1u << co; if (s0 < 0) osg |= 1u << co; }
            if (s1 != 0) { onz |= 1u << (co + 1); if (s1 < 0) osg |= 1u << (co + 1); }
        }
        ax[t] = make_uint2(onz, osg);
    }
    __syncthreads();
    // conv4: o = pos*32+co
    for (int o = t; o < 1152; o += 256) {
        int pos = o >> 5, co = o & 31;
        int hol = pos / 9, w = pos % 9;
        int cnt = 0, neg = 0;
#pragma unroll
        for (int kh = 0; kh < 5; ++kh) {
            uint2 av = ax[(5 * hol + kh) * 9 + w];
            uint2 wv = w4L[kh * 32 + co];
            unsigned both = av.x & wv.x;
            cnt += __popc(both);
            neg += __popc((av.y ^ wv.y) & both);
        }
        float val = (float)(cnt - 2 * neg);
        sArr[o] = val;
        p2[(((long)n * 396 + (4 * hb + hol) * 9 + w) << 5) + co] = val;
    }
    __syncthreads();
    if (t < 32) {
        double s = 0, q = 0;
        for (int pos = 0; pos < 36; ++pos) {
            double v = (double)sArr[pos * 32 + t];
            s += v; q += v * v;
        }
        long blk = (long)hb * 512 + n;
        part[((long)t * 5632 + blk) * 2] = s;
        part[((long)t * 5632 + blk) * 2 + 1] = q;
    }
}

// ---------------- stage 3: grid(4,512); 198-thread conv5; w6 [kh][co] ----------------
__global__ void stage3_kernel(const float* __restrict__ p2, const float* __restrict__ mean,
    const float* __restrict__ rstd, const float* __restrict__ g, const float* __restrict__ b,
    const float* __restrict__ ap, const unsigned* __restrict__ w5n, const unsigned* __restrict__ w5s,
    const unsigned* __restrict__ w6n, const unsigned* __restrict__ w6s, float* __restrict__ p3,
    double* __restrict__ part) {
    int ho = blockIdx.x;   // 0..3
    int n = blockIdx.y;
    float a = ap[0];
    __shared__ __align__(16) uint2 qx[189];
    __shared__ __align__(16) uint2 ax[99 * 2];
    __shared__ __align__(16) uint2 w5L[704];     // [kh*64+co]
    __shared__ __align__(16) uint2 w6L[1408];    // [(kh*64+co)*2+wi]
    __shared__ float sArr[576];
    int t = threadIdx.x;
    for (int i = t; i < 704; i += 256) {
        int kh = i / 64, co = i % 64;
        w5L[i] = make_uint2(w5n[co * 11 + kh], w5s[co * 11 + kh]);
    }
    for (int i = t; i < 1408; i += 256) {
        int pair = i >> 1, wi = i & 1;
        int kh = pair / 64, co = pair % 64;
        w6L[i] = make_uint2(w6n[(co * 11 + kh) * 2 + wi], w6s[(co * 11 + kh) * 2 + wi]);
    }
    if (t < 189) {
        int rl = t / 9, w = t % 9;
        int r = 11 * ho - 5 + rl;
        unsigned nz = 0, sg = 0;
        if (r >= 0 && r < 44) {
            const float4* src = (const float4*)(p2 + (((long)n * 396 + r * 9 + w) << 5));
            float4 v4[8];
#pragma unroll
            for (int q4 = 0; q4 < 8; ++q4) v4[q4] = src[q4];
            const float* vals = (const float*)v4;
#pragma unroll
            for (int ci = 0; ci < 32; ++ci) {
                float bnv = (vals[ci] - mean[ci]) * rstd[ci] * g[ci] + b[ci];
                float pr = bnv < 0.f ? a * bnv : bnv;
                if (pr != 0.f) { nz |= 1u << ci; if (pr < 0.f) sg |= 1u << ci; }
            }
        }
        qx[t] = make_uint2(nz, sg);
    }
    __syncthreads();
    // conv5: unit = (p, wi); 198 threads
    if (t < 198) {
        int p = t >> 1, wi = t & 1;
        int jl = p / 9, w = p % 9;
        uint2 xv[11];
#pragma unroll
        for (int kh = 0; kh < 11; ++kh) xv[kh] = qx[(jl + kh) * 9 + w];
        unsigned onz = 0, osg = 0;
        for (int jj = 0; jj < 32; jj += 2) {
            int co0 = wi * 32 + jj;
            int c0 = 0, n0 = 0, c1 = 0, n1 = 0;
#pragma unroll
            for (int kh = 0; kh < 11; ++kh) {
                const uint4 wv = *(const uint4*)&w5L[kh * 64 + co0];
                unsigned b0 = xv[kh].x & wv.x;
                c0 += __popc(b0);
                n0 += __popc((xv[kh].y ^ wv.y) & b0);
                unsigned b1 = xv[kh].x & wv.z;
                c1 += __popc(b1);
                n1 += __popc((xv[kh].y ^ wv.w) & b1);
            }
            int s0 = c0 - 2 * n0, s1 = c1 - 2 * n1;
            if (s0 != 0) { onz |= 1u << jj; if (s0 < 0) osg |= 1u << jj; }
            if (s1 != 0) { onz |= 1u << (jj + 1); if (s1 < 0) osg |= 1u << (jj + 1); }
        }
        ax[p * 2 + wi] = make_uint2(onz, osg);
    }
    __syncthreads();
    // conv6: o = w*64+co
    for (int o = t; o < 576; o += 256) {
        int co = o & 63, w = o >> 6;
        int cA = 0, nA = 0, cB = 0, nB = 0;
        for (int kh = 0; kh < 11; ++kh) {
            const uint4 av = *(const uint4*)&ax[(kh * 9 + w) * 2];
            const uint4 wv = *(const uint4*)&w6L[(kh * 64 + co) * 2];
            unsigned b0 = av.x & wv.x;
            cA += __popc(b0);
            nA += __popc((av.y ^ wv.y) & b0);
            unsigned b1 = av.z & wv.z;
            cB += __popc(b1);
            nB += __popc((av.w ^ wv.w) & b1);
        }
        float val = (float)((cA + cB) - 2 * (nA + nB));
        sArr[o] = val;
        p3[(((long)n * 36 + ho * 9 + w) << 6) + co] = val;
    }
    __syncthreads();
    if (t < 64) {
        double s = 0, q = 0;
        for (int w = 0; w < 9; ++w) {
            double v = (double)sArr[w * 64 + t];
            s += v; q += v * v;
        }
        long blk = (long)ho * 512 + n;
        part[((long)t * 2048 + blk) * 2] = s;
        part[((long)t * 2048 + blk) * 2 + 1] = q;
    }
}

// ---------------- stage 4: grid(4,512) ----------------
__global__ void stage4_kernel(const float* __restrict__ p3, const float* __restrict__ mean,
    const float* __restrict__ rstd, const float* __restrict__ g, const float* __restrict__ b,
    const float* __restrict__ ap, const unsigned* __restrict__ w7n, const unsigned* __restrict__ w7s,
    const unsigned* __restrict__ w8n, const unsigned* __restrict__ w8s, float* __restrict__ p4,
    double* __restrict__ part) {
    int h = blockIdx.x;   // 0..3
    int n = blockIdx.y;
    float a = ap[0];
    __shared__ unsigned q[9 * 4];
    __shared__ signed char strit[9 * 128];
    __shared__ unsigned an[9 * 4], ag[9 * 4];
    __shared__ float sArr[384];
    int t = threadIdx.x;
    if (t < 18) {
        int w = t >> 1, half = t & 1;
        const float4* src = (const float4*)(p3 + (((long)n * 36 + h * 9 + w) << 6) + half * 32);
        float4 v4[8];
#pragma unroll
        for (int q4 = 0; q4 < 8; ++q4) v4[q4] = src[q4];
        const float* vals = (const float*)v4;
        unsigned nz = 0, sg = 0;
#pragma unroll
        for (int j = 0; j < 32; ++j) {
            int ci = half * 32 + j;
            float bnv = (vals[j] - mean[ci]) * rstd[ci] * g[ci] + b[ci];
            float pr = bnv < 0.f ? a * bnv : bnv;
            if (pr != 0.f) { nz |= 1u << j; if (pr < 0.f) sg |= 1u << j; }
        }
        q[w * 4 + half] = nz; q[w * 4 + 2 + half] = sg;
    }
    __syncthreads();
    for (int o = t; o < 1152; o += 256) {
        int w = o / 128, co = o % 128;
        int cnt = 0, neg = 0;
        for (int kw = 0; kw < 3; ++kw) {
            int wl = w + kw - 1;
            if (wl < 0 || wl >= 9) continue;
#pragma unroll
            for (int iw = 0; iw < 2; ++iw) {
                unsigned both = q[wl * 4 + iw] & w7n[(co * 3 + kw) * 2 + iw];
                cnt += __popc(both);
                neg += __popc((q[wl * 4 + 2 + iw] ^ w7s[(co * 3 + kw) * 2 + iw]) & both);
            }
        }
        int s = cnt - 2 * neg;
        strit[o] = (signed char)((s > 0) - (s < 0));
    }
    __syncthreads();
    if (t < 36) {
        int w = t >> 2, wi = t & 3;
        unsigned nz = 0, sg = 0;
        for (int j = 0; j < 32; ++j) {
            int tr = strit[w * 128 + wi * 32 + j];
            if (tr) { nz |= 1u << j; if (tr < 0) sg |= 1u << j; }
        }
        an[w * 4 + wi] = nz; ag[w * 4 + wi] = sg;
    }
    __syncthreads();
    for (int o = t; o < 384; o += 256) {
        int wo = o >> 7, co = o & 127;
        int cnt = 0, neg = 0;
        for (int kw = 0; kw < 3; ++kw) {
            int wl = 3 * wo + kw;
#pragma unroll
            for (int iw = 0; iw < 4; ++iw) {
                unsigned both = an[wl * 4 + iw] & w8n[(co * 3 + kw) * 4 + iw];
                cnt += __popc(both);
                neg += __popc((ag[wl * 4 + iw] ^ w8s[(co * 3 + kw) * 4 + iw]) & both);
            }
        }
        float val = (float)(cnt - 2 * neg);
        sArr[o] = val;
        p4[(((long)n * 12 + h * 3 + wo) << 7) + co] = val;
    }
    __syncthreads();
    if (t < 128) {
        double s = 0, qd = 0;
        for (int wo = 0; wo < 3; ++wo) {
            double v = (double)sArr[wo * 128 + t];
            s += v; qd += v * v;
        }
        long blk = (long)h * 512 + n;
        part[((long)t * 2048 + blk) * 2] = s;
        part[((long)t * 2048 + blk) * 2 + 1] = qd;
    }
}

// ---------------- stage 5: grid(4,512) ----------------
__global__ void stage5_kernel(const float* __restrict__ p4, const float* __restrict__ mean,
    const float* __restrict__ rstd, const float* __restrict__ g, const float* __restrict__ b,
    const float* __restrict__ ap, const unsigned* __restrict__ w9n, const unsigned* __restrict__ w9s,
    const unsigned* __restrict__ w10n, const unsigned* __restrict__ w10s, float* __restrict__ p5,
    double* __restrict__ part) {
    int h = blockIdx.x;   // 0..3
    int n = blockIdx.y;
    float a = ap[0];
    __shared__ unsigned q[3 * 8];
    __shared__ signed char strit[3 * 256];
    __shared__ unsigned an[3 * 8], ag[3 * 8];
    int t = threadIdx.x;
    if (t < 12) {
        int w = t >> 2, wq = t & 3;
        const float4* src = (const float4*)(p4 + (((long)n * 12 + h * 3 + w) << 7) + wq * 32);
        float4 v4[8];
#pragma unroll
        for (int q4 = 0; q4 < 8; ++q4) v4[q4] = src[q4];
        const float* vals = (const float*)v4;
        unsigned nz = 0, sg = 0;
#pragma unroll
        for (int j = 0; j < 32; ++j) {
            int ci = wq * 32 + j;
            float bnv = (vals[j] - mean[ci]) * rstd[ci] * g[ci] + b[ci];
            float pr = bnv < 0.f ? a * bnv : bnv;
            if (pr != 0.f) { nz |= 1u << j; if (pr < 0.f) sg |= 1u << j; }
        }
        q[w * 8 + wq] = nz; q[w * 8 + 4 + wq] = sg;
    }
    __syncthreads();
    for (int o = t; o < 768; o += 256) {
        int w = o / 256, co = o % 256;
        int cnt = 0, neg = 0;
        for (int kw = 0; kw < 3; ++kw) {
            int wl = w + kw - 1;
            if (wl < 0 || wl >= 3) continue;
#pragma unroll
            for (int iw = 0; iw < 4; ++iw) {
                unsigned both = q[wl * 8 + iw] & w9n[(co * 3 + kw) * 4 + iw];
                cnt += __popc(both);
                neg += __popc((q[wl * 8 + 4 + iw] ^ w9s[(co * 3 + kw) * 4 + iw]) & both);
            }
        }
        int s = cnt - 2 * neg;
        strit[o] = (signed char)((s > 0) - (s < 0));
    }
    __syncthreads();
    if (t < 24) {
        int w = t >> 3, wi = t & 7;
        unsigned nz = 0, sg = 0;
        for (int j = 0; j < 32; ++j) {
            int tr = strit[w * 256 + wi * 32 + j];
            if (tr) { nz |= 1u << j; if (tr < 0) sg |= 1u << j; }
        }
        an[w * 8 + wi] = nz; ag[w * 8 + wi] = sg;
    }
    __syncthreads();
    if (t < 256) {
        int co = t;
        int cnt = 0, neg = 0;
        for (int kw = 0; kw < 3; ++kw) {
#pragma unroll
            for (int iw = 0; iw < 8; ++iw) {
                unsigned both = an[kw * 8 + iw] & w10n[(co * 3 + kw) * 8 + iw];
                cnt += __popc(both);
                neg += __popc((ag[kw * 8 + iw] ^ w10s[(co * 3 + kw) * 8 + iw]) & both);
            }
        }
        float val = (float)(cnt - 2 * neg);
        p5[(long)n * 1024 + co * 4 + h] = val;
        long blk = (long)h * 512 + n;
        double v = (double)val;
        part[((long)co * 2048 + blk) * 2] = v;
        part[((long)co * 2048 + blk) * 2 + 1] = v * v;
    }
}

// ---------------- fc1: grid(512), wave-per-output (round-13 proven) ----------------
__global__ void fc1_kernel(const float* __restrict__ p5, const float* __restrict__ mean,
                           const float* __restrict__ rstd, const float* __restrict__ g,
                           const float* __restrict__ b, const float* __restrict__ ap,
                           const float* __restrict__ sfc1, float* __restrict__ h1) {
    int n = blockIdx.x;
    float a = ap[0];
    __shared__ float hv[1024];
    int t = threadIdx.x;
    for (int idx = t; idx < 1024; idx += 256) {
        int c = idx >> 2;
        float v = p5[n * 1024 + idx];
        float bnv = (v - mean[c]) * rstd[c] * g[c] + b[c];
        hv[idx] = bnv < 0.f ? a * bnv : bnv;
    }
    __syncthreads();
    int wave = t >> 6, lane = t & 63;
    float hr[16];
#pragma unroll
    for (int m = 0; m < 16; ++m) hr[m] = hv[lane * 16 + m];
    for (int jj = 0; jj < 64; ++jj) {
        int j = wave * 64 + jj;
        const float4* wr = (const float4*)(sfc1 + (j << 10) + (lane << 4));
        double s = 0.0;
#pragma unroll
        for (int q4 = 0; q4 < 4; ++q4) {
            float4 wv = wr[q4];
            s += (double)(hr[q4 * 4 + 0] * wv.x);
            s += (double)(hr[q4 * 4 + 1] * wv.y);
            s += (double)(hr[q4 * 4 + 2] * wv.z);
            s += (double)(hr[q4 * 4 + 3] * wv.w);
        }
#pragma unroll
        for (int off = 32; off > 0; off >>= 1) s += __shfl_down(s, off, 64);
        if (lane == 0) h1[n * 256 + j] = (float)s;
    }
}

// ---------------- fc2 ----------------
__global__ void fc2_kernel(const float* __restrict__ h1, const float* __restrict__ mean,
                           const float* __restrict__ rstd, const float* __restrict__ g,
                           const float* __restrict__ b, const float* __restrict__ ap,
                           const float* __restrict__ sfc2, float* __restrict__ h2) {
    int n = blockIdx.x;
    float a = ap[0];
    __shared__ float sv[256];
    int t = threadIdx.x;
    if (t < 256) {
        float v = h1[n * 256 + t];
        float bnv = (v - mean[t]) * rstd[t] * g[t] + b[t];
        float pr = bnv < 0.f ? a * bnv : bnv;
        sv[t] = fsign(pr);
    }
    __syncthreads();
    if (t < 64) {
        float s = 0.f;
        for (int k = 0; k < 256; ++k) s += sv[k] * sfc2[t * 256 + k];
        h2[n * 64 + t] = s;
    }
}

// ---------------- fc3 ----------------
__global__ void fc3_kernel(const float* __restrict__ h2, const float* __restrict__ mean,
                           const float* __restrict__ rstd, const float* __restrict__ g,
                           const float* __restrict__ b, const float* __restrict__ ap,
                           const float* __restrict__ sfc3, float* __restrict__ out) {
    int n = blockIdx.x;
    float a = ap[0];
    __shared__ float sv[64];
    int t = threadIdx.x;
    if (t < 64) {
        float v = h2[n * 64 + t];
        float bnv = (v - mean[t]) * rstd[t] * g[t] + b[t];
        float pr = bnv < 0.f ? a * bnv : bnv;
        sv[t] = fsign(pr);
    }
    __syncthreads();
    if (t < 2) {
        float s = 0.f;
        for (int k = 0; k < 64; ++k) s += sv[k] * sfc3[t * 64 + k];
        out[n * 2 + t] = s;
    }
}

extern "C" void kernel_launch(void* const* d_in, const int* in_sizes, int n_in,
                              void* d_out, int out_size, void* d_ws, size_t ws_size,
                              hipStream_t stream) {
    const float* x = (const float*)d_in[0];
    const float* G[8] = {nullptr, (const float*)d_in[11], (const float*)d_in[14],
                         (const float*)d_in[17], (const float*)d_in[20], (const float*)d_in[23],
                         (const float*)d_in[29], (const float*)d_in[31]};
    const float* B[8] = {nullptr, (const float*)d_in[12], (const float*)d_in[15],
                         (const float*)d_in[18], (const float*)d_in[21], (const float*)d_in[24],
                         (const float*)d_in[30], (const float*)d_in[32]};
    const float* A[8] = {nullptr, (const float*)d_in[13], (const float*)d_in[16],
                         (const float*)d_in[19], (const float*)d_in[22], (const float*)d_in[25],
                         (const float*)d_in[33], (const float*)d_in[34]};

    float* ws = (float*)d_ws;
    size_t off = 0;
    const int fsz[3] = {262144, 16384, 128};
    float* fw[3];
    for (int i = 0; i < 3; ++i) { fw[i] = ws + off; off += (size_t)fsz[i]; }
    float* sfc1 = fw[0]; float* sfc2 = fw[1]; float* sfc3 = fw[2];
    float* wc = ws + off; off += 208;

    const int psz[8] = {160, 160, 704, 1408, 768, 1536, 3072, 6144};
    unsigned* pn[8]; unsigned* pg[8];
    for (int i = 0; i < 8; ++i) {
        pn[i] = (unsigned*)(ws + off); off += (size_t)psz[i];
        pg[i] = (unsigned*)(ws + off); off += (size_t)psz[i];
    }

    float* p1 = ws + off; off += 16220160;   // (n,1980,16)
    float* p2 = ws + off; off += 6488064;    // (n,396,32)
    float* p3 = ws + off; off += 1179648;    // (n,36,64)
    float* p4 = ws + off; off += 786432;     // (n,12,128)
    float* p5 = ws + off; off += 524288;     // (n,1024)
    float* h1 = ws + off; off += 131072;
    float* h2 = ws + off; off += 32768;
    float* mean1 = ws + off; off += 16;  float* rstd1 = ws + off; off += 16;
    float* mean2 = ws + off; off += 32;  float* rstd2 = ws + off; off += 32;
    float* mean3 = ws + off; off += 64;  float* rstd3 = ws + off; off += 64;
    float* mean4 = ws + off; off += 128; float* rstd4 = ws + off; off += 128;
    float* mean5 = ws + off; off += 256; float* rstd5 = ws + off; off += 256;
    float* mean6 = ws + off; off += 256; float* rstd6 = ws + off; off += 256;
    float* mean7 = ws + off; off += 64;  float* rstd7 = ws + off; off += 64;
    if (off & 1) off += 1;  // 8B-align
    double* part = (double*)(ws + off); off += 2 * 1048576;

    // 1. sign fc weights + composite stage1 weights
    WPtrs wp;
    const int fsrc_idx[3] = {26, 27, 28};
    for (int i = 0; i < 3; ++i) {
        wp.src[i] = (const float*)d_in[fsrc_idx[i]];
        wp.dst[i] = fw[i];
        wp.n[i] = fsz[i];
    }
    hipLaunchKernelGGL(sign_weights_kernel, dim3(32, 3), dim3(256), 0, stream, wp);
    hipLaunchKernelGGL(build_wc_kernel, dim3(1), dim3(256), 0, stream,
                       (const float*)d_in[1], (const float*)d_in[2], wc);

    // 2. pack conv weights w3..w10
    PWall pa;
    const int cout_[8] = {32, 32, 64, 64, 128, 128, 256, 256};
    const int cin_[8]  = {16, 32, 32, 64, 64, 128, 128, 256};
    const int kk_[8]   = {5, 5, 11, 11, 3, 3, 3, 3};
    for (int i = 0; i < 8; ++i) {
        pa.l[i].src = (const float*)d_in[3 + i];
        pa.l[i].dnz = pn[i];
        pa.l[i].dsg = pg[i];
        pa.l[i].cout = cout_[i];
        pa.l[i].cin = cin_[i];
        pa.l[i].k = kk_[i];
        pa.l[i].nw = (cin_[i] + 31) / 32;
    }
    hipLaunchKernelGGL(pack_weights_kernel, dim3(4, 8), dim3(256), 0, stream, pa);

    // 3. stage1 -> p1t + partials; finalize bn1
    hipLaunchKernelGGL(stage1_kernel, dim3(8, 512), dim3(256), 0, stream, x, wc, p1, part);
    hipLaunchKernelGGL(stats_finalp, dim3(16), dim3(256), 0, stream, part, 4096,
                       (long)512 * 1980, mean1, rstd1);

    // 4. stage2 -> p2t + partials; finalize bn2
    hipLaunchKernelGGL(stage2_kernel, dim3(11, 512), dim3(256), 0, stream, p1, mean1, rstd1,
                       G[1], B[1], A[1], pn[0], pg[0], pn[1], pg[1], p2, part);
    hipLaunchKernelGGL(stats_finalp, dim3(32), dim3(256), 0, stream, part, 5632,
                       (long)512 * 396, mean2, rstd2);

    // 5. stage3 -> p3t + partials; finalize bn3
    hipLaunchKernelGGL(stage3_kernel, dim3(4, 512), dim3(256), 0, stream, p2, mean2, rstd2,
                       G[2], B[2], A[2], pn[2], pg[2], pn[3], pg[3], p3, part);
    hipLaunchKernelGGL(stats_finalp, dim3(64), dim3(256), 0, stream, part, 2048,
                       (long)512 * 36, mean3, rstd3);

    // 6. stage4 -> p4t + partials; finalize bn4
    hipLaunchKernelGGL(stage4_kernel, dim3(4, 512), dim3(256), 0, stream, p3, mean3, rstd3,
                       G[3], B[3], A[3], pn[4], pg[4], pn[5], pg[5], p4, part);
    hipLaunchKernelGGL(stats_finalp, dim3(128), dim3(256), 0, stream, part, 2048,
                       (long)512 * 12, mean4, rstd4);

    // 7. stage5 -> p5 + partials; finalize bn5
    hipLaunchKernelGGL(stage5_kernel, dim3(4, 512), dim3(256), 0, stream, p4, mean4, rstd4,
                       G[4], B[4], A[4], pn[6], pg[6], pn[7], pg[7], p5, part);
    hipLaunchKernelGGL(stats_finalp, dim3(256), dim3(256), 0, stream, part, 2048,
                       (long)512 * 4, mean5, rstd5);

    // 8. fc1 -> h1, stats
    hipLaunchKernelGGL(fc1_kernel, dim3(512), dim3(256), 0, stream, p5, mean5, rstd5,
                       G[5], B[5], A[5], sfc1, h1);
    hipLaunchKernelGGL(stats_bn1d, dim3(256), dim3(64), 0, stream, h1, 256, 512, mean6, rstd6);

    // 9. fc2 -> h2, stats
    hipLaunchKernelGGL(fc2_kernel, dim3(512), dim3(256), 0, stream, h1, mean6, rstd6,
                       G[6], B[6], A[6], sfc2, h2);
    hipLaunchKernelGGL(stats_bn1d, dim3(64), dim3(64), 0, stream, h2, 64, 512, mean7, rstd7);

    // 10. fc3 -> d_out
    hipLaunchKernelGGL(fc3_kernel, dim3(512), dim3(256), 0, stream, h2, mean7, rstd7,
                       G[7], B[7], A[7], sfc3, (float*)d_out);
}